// Round 1
// baseline (271.942 us; speedup 1.0000x reference)
//
#include <hip/hip_runtime.h>

#define K7   7
#define PAD3 3
#define C64  64
#define CRED 32          // C/2
#define G16  16
#define GC4  4
#define EPSV 1e-5f

#define TILE 8                      // 8x8 pixels per block
#define HALO (TILE + K7 - 1)        // 14
#define YRS  15                     // ytile row stride (floats)
#define YCH  (HALO * YRS)           // 210 floats per channel
#define TST  36                     // t_lds per-pixel stride (144B, 16B aligned)

__global__ __launch_bounds__(256, 2)
void involution_fused(const float* __restrict__ x, const float* __restrict__ y,
                      const float* __restrict__ w1, const float* __restrict__ b1,
                      const float* __restrict__ gma, const float* __restrict__ bta,
                      const float* __restrict__ mu,  const float* __restrict__ var,
                      const float* __restrict__ w2,  const float* __restrict__ b2,
                      float* __restrict__ out)
{
    __shared__ float ytile[C64 * YCH];    // 53760 B
    __shared__ float t_lds[64 * TST];     // 9216 B

    const int tid = threadIdx.x;
    const int bx = blockIdx.x, by = blockIdx.y, bz = blockIdx.z;
    const int gh0 = by * TILE, gw0 = bx * TILE;

    // ---- stage y halo tile: 64 ch x 14 x 14, zero-padded at image borders ----
    for (int li = tid; li < C64 * HALO * HALO; li += 256) {
        int c   = li / (HALO * HALO);
        int rem = li - c * (HALO * HALO);
        int r   = rem / HALO;
        int col = rem - r * HALO;
        int grow = gh0 - PAD3 + r;
        int gcol = gw0 - PAD3 + col;
        float v = 0.f;
        if ((unsigned)grow < 128u && (unsigned)gcol < 128u)
            v = y[((size_t)(bz * C64 + c) << 14) + (grow << 7) + gcol];
        ytile[c * YCH + r * YRS + col] = v;
    }

    // ---- phase 1: conv1 (1x1) + BN(eval) + ReLU -> t_lds ----
    const int p  = tid & 63;          // pixel within 8x8 tile
    const int ph = p >> 3, pw = p & 7;
    const int oq = __builtin_amdgcn_readfirstlane(tid >> 6);  // wave id, uniform
    const int pix = ((gh0 + ph) << 7) + (gw0 + pw);
    {
        float dot[8] = {0,0,0,0,0,0,0,0};
        const float* w1q = w1 + oq * 8 * C64;     // 8 rows of w1 for this wave
        const float* xp  = x + ((size_t)(bz * C64) << 14) + pix;
        #pragma unroll 8
        for (int c = 0; c < C64; ++c) {
            float xc = xp[(size_t)c << 14];
            #pragma unroll
            for (int j = 0; j < 8; ++j) dot[j] += w1q[j * C64 + c] * xc;
        }
        #pragma unroll
        for (int j = 0; j < 8; ++j) {
            int o = oq * 8 + j;
            float sv = gma[o] * rsqrtf(var[o] + EPSV);
            float bb = (b1[o] - mu[o]) * sv + bta[o];
            t_lds[p * TST + o] = fmaxf(dot[j] * sv + bb, 0.f);
        }
    }
    __syncthreads();

    // ---- phase 2: per-pixel dynamic kernels + depthwise aggregation ----
    float tv[32];
    {
        const float4* tp = (const float4*)&t_lds[p * TST];
        #pragma unroll
        for (int q = 0; q < 8; ++q) {
            float4 v = tp[q];
            tv[q*4+0] = v.x; tv[q*4+1] = v.y; tv[q*4+2] = v.z; tv[q*4+3] = v.w;
        }
    }

    #pragma unroll 1
    for (int gi = 0; gi < 4; ++gi) {
        const int g = oq * 4 + gi;                 // wave-uniform group index
        const float* w2g = w2 + g * 49 * CRED;
        const float* b2g = b2 + g * 49;
        const float* yt0 = ytile + (g * GC4) * YCH + ph * YRS + pw;
        float acc0 = 0, acc1 = 0, acc2 = 0, acc3 = 0;
        int k = 0;
        #pragma unroll 1
        for (int di = 0; di < K7; ++di) {
            #pragma unroll
            for (int dj = 0; dj < K7; ++dj, ++k) {
                const float* row = w2g + k * CRED;   // uniform -> s_load
                float s0 = b2g[k], s1 = 0.f, s2 = 0.f, s3 = 0.f;
                #pragma unroll
                for (int o = 0; o < 32; o += 4) {
                    s0 += row[o+0] * tv[o+0];
                    s1 += row[o+1] * tv[o+1];
                    s2 += row[o+2] * tv[o+2];
                    s3 += row[o+3] * tv[o+3];
                }
                float wgt = (s0 + s1) + (s2 + s3);
                const float* yt = yt0 + di * YRS + dj;
                acc0 += wgt * yt[0 * YCH];
                acc1 += wgt * yt[1 * YCH];
                acc2 += wgt * yt[2 * YCH];
                acc3 += wgt * yt[3 * YCH];
            }
        }
        size_t ob = ((size_t)(bz * C64 + g * GC4) << 14) + pix;
        out[ob]             = acc0;
        out[ob + 1u * 16384] = acc1;
        out[ob + 2u * 16384] = acc2;
        out[ob + 3u * 16384] = acc3;
    }
}

extern "C" void kernel_launch(void* const* d_in, const int* in_sizes, int n_in,
                              void* d_out, int out_size, void* d_ws, size_t ws_size,
                              hipStream_t stream) {
    const float* x   = (const float*)d_in[0];
    const float* y   = (const float*)d_in[1];
    const float* w1  = (const float*)d_in[2];
    const float* b1  = (const float*)d_in[3];
    const float* gma = (const float*)d_in[4];
    const float* bta = (const float*)d_in[5];
    const float* mu  = (const float*)d_in[6];
    const float* var = (const float*)d_in[7];
    const float* w2  = (const float*)d_in[8];
    const float* b2  = (const float*)d_in[9];
    float* out = (float*)d_out;

    dim3 grid(128 / TILE, 128 / TILE, 4);   // 16 x 16 x 4 = 1024 blocks
    dim3 block(256);
    hipLaunchKernelGGL(involution_fused, grid, block, 0, stream,
                       x, y, w1, b1, gma, bta, mu, var, w2, b2, out);
}

// Round 2
// 154.607 us; speedup vs baseline: 1.7589x; 1.7589x over previous
//
#include <hip/hip_runtime.h>

#define K7   7
#define PAD3 3
#define C64  64
#define CRED 32          // C/2
#define GC4  4
#define EPSV 1e-5f

#define TILE 8                      // 8x8 pixels per block
#define HALO 14                     // TILE + K7 - 1
#define NPIX (HALO * HALO)          // 196
#define NCH  32                     // y-channels per block (half of 64)
#define NSL  8                      // channel-groups (slots) per block
#define TST  36                     // t_lds per-pixel stride (144B, 16B aligned)

__global__ __launch_bounds__(256, 4)
void involution_fused(const float* __restrict__ x, const float* __restrict__ y,
                      const float* __restrict__ w1, const float* __restrict__ b1,
                      const float* __restrict__ gma, const float* __restrict__ bta,
                      const float* __restrict__ mu,  const float* __restrict__ var,
                      const float* __restrict__ w2,  const float* __restrict__ b2,
                      float* __restrict__ out)
{
    // [pixel][slot][4ch], slot rotated by pixel: ch-group cg stored at slot (cg+pix)&7
    __shared__ __align__(16) float ytile[NPIX * NCH];   // 25088 B
    __shared__ __align__(16) float t_lds[64 * TST];     // 9216 B

    const int tid = threadIdx.x;
    const int bx = blockIdx.x, by = blockIdx.y, bz = blockIdx.z;
    const int b = bz >> 1, half = bz & 1;
    const int gh0 = by * TILE, gw0 = bx * TILE;
    const int c0 = half * NCH;                 // first y channel of this block

    // ---- stage y halo tile: 32 ch x 14 x 14, swizzled channel-inner layout ----
    for (int li = tid; li < NCH * NPIX; li += 256) {
        int c   = li / NPIX;                   // local channel 0..31
        int pix = li - c * NPIX;               // 0..195
        int r   = pix / HALO;
        int col = pix - r * HALO;
        int grow = gh0 - PAD3 + r;
        int gcol = gw0 - PAD3 + col;
        float v = 0.f;
        if ((unsigned)grow < 128u && (unsigned)gcol < 128u)
            v = y[((size_t)(b * C64 + c0 + c) << 14) + (grow << 7) + gcol];
        int slot = ((c >> 2) + pix) & 7;
        ytile[pix * NCH + slot * 4 + (c & 3)] = v;
    }

    // ---- phase 1: conv1 (1x1) + BN(eval) + ReLU -> t_lds (all 32 t-channels) ----
    const int p  = tid & 63;                   // pixel within 8x8 tile
    const int ph = p >> 3, pw = p & 7;
    const int oq = __builtin_amdgcn_readfirstlane(tid >> 6);  // wave id, uniform
    const int pix = ((gh0 + ph) << 7) + (gw0 + pw);
    {
        float dot[8] = {0,0,0,0,0,0,0,0};
        const float* w1q = w1 + oq * 8 * C64;  // 8 rows of w1 for this wave
        const float* xp  = x + ((size_t)(b * C64) << 14) + pix;
        #pragma unroll 8
        for (int c = 0; c < C64; ++c) {
            float xc = xp[(size_t)c << 14];
            #pragma unroll
            for (int j = 0; j < 8; ++j) dot[j] += w1q[j * C64 + c] * xc;
        }
        #pragma unroll
        for (int j = 0; j < 8; ++j) {
            int o = oq * 8 + j;
            float sv = gma[o] * rsqrtf(var[o] + EPSV);
            float bb = (b1[o] - mu[o]) * sv + bta[o];
            t_lds[p * TST + o] = fmaxf(dot[j] * sv + bb, 0.f);
        }
    }
    __syncthreads();

    // ---- phase 2: per-pixel dynamic kernels + depthwise aggregation ----
    float tv[32];
    {
        const float4* tp = (const float4*)&t_lds[p * TST];
        #pragma unroll
        for (int q = 0; q < 8; ++q) {
            float4 v = tp[q];
            tv[q*4+0] = v.x; tv[q*4+1] = v.y; tv[q*4+2] = v.z; tv[q*4+3] = v.w;
        }
    }

    #pragma unroll 1
    for (int lgi = 0; lgi < 2; ++lgi) {
        const int lg = oq * 2 + lgi;           // local group 0..7 (wave-uniform)
        const int g  = half * NSL + lg;        // global group 0..15
        const float* w2g = w2 + g * 49 * CRED;
        const float* b2g = b2 + g * 49;
        float acc0 = 0, acc1 = 0, acc2 = 0, acc3 = 0;
        int k = 0;
        #pragma unroll 1
        for (int di = 0; di < K7; ++di) {
            #pragma unroll
            for (int dj = 0; dj < K7; ++dj, ++k) {
                const float* row = w2g + k * CRED;   // uniform -> s_load
                float s0 = b2g[k], s1 = 0.f, s2 = 0.f, s3 = 0.f;
                #pragma unroll
                for (int o = 0; o < 32; o += 4) {
                    s0 += row[o+0] * tv[o+0];
                    s1 += row[o+1] * tv[o+1];
                    s2 += row[o+2] * tv[o+2];
                    s3 += row[o+3] * tv[o+3];
                }
                float wgt = (s0 + s1) + (s2 + s3);
                int tp2 = (ph + di) * HALO + (pw + dj);
                const float4 y4 = *(const float4*)&ytile[tp2 * NCH + (((lg + tp2) & 7) << 2)];
                acc0 += wgt * y4.x;
                acc1 += wgt * y4.y;
                acc2 += wgt * y4.z;
                acc3 += wgt * y4.w;
            }
        }
        size_t ob = ((size_t)(b * C64 + g * GC4) << 14) + pix;
        out[ob]              = acc0;
        out[ob + 1u * 16384] = acc1;
        out[ob + 2u * 16384] = acc2;
        out[ob + 3u * 16384] = acc3;
    }
}

extern "C" void kernel_launch(void* const* d_in, const int* in_sizes, int n_in,
                              void* d_out, int out_size, void* d_ws, size_t ws_size,
                              hipStream_t stream) {
    const float* x   = (const float*)d_in[0];
    const float* y   = (const float*)d_in[1];
    const float* w1  = (const float*)d_in[2];
    const float* b1  = (const float*)d_in[3];
    const float* gma = (const float*)d_in[4];
    const float* bta = (const float*)d_in[5];
    const float* mu  = (const float*)d_in[6];
    const float* var = (const float*)d_in[7];
    const float* w2  = (const float*)d_in[8];
    const float* b2  = (const float*)d_in[9];
    float* out = (float*)d_out;

    dim3 grid(128 / TILE, 128 / TILE, 8);   // 16 x 16 x (4 batch * 2 halves)
    dim3 block(256);
    hipLaunchKernelGGL(involution_fused, grid, block, 0, stream,
                       x, y, w1, b1, gma, bta, mu, var, w2, b2, out);
}

// Round 3
// 146.170 us; speedup vs baseline: 1.8605x; 1.0577x over previous
//
#include <hip/hip_runtime.h>

#define K7   7
#define PAD3 3
#define C64  64
#define CRED 32          // C/2
#define GC4  4
#define EPSV 1e-5f

#define TILE 8                      // 8x8 pixels per block
#define HALO 14                     // TILE + K7 - 1
#define NPIX (HALO * HALO)          // 196
#define NCH  32                     // y-channels per block (half of 64)
#define NSL  8                      // channel-groups (slots) per block
#define TSTH 40                     // t_lds row stride in f16 (80B, 16B-aligned)

typedef _Float16 half8 __attribute__((ext_vector_type(8)));
typedef float    f32x4 __attribute__((ext_vector_type(4)));

__global__ __launch_bounds__(256, 4)
void involution_mfma(const float* __restrict__ x, const float* __restrict__ y,
                     const float* __restrict__ w1, const float* __restrict__ b1,
                     const float* __restrict__ gma, const float* __restrict__ bta,
                     const float* __restrict__ mu,  const float* __restrict__ var,
                     const float* __restrict__ w2,  const float* __restrict__ b2,
                     float* __restrict__ out)
{
    // [pixel][slot][4ch], slot rotated by pixel: ch-group cg stored at slot (cg+pix)&7
    __shared__ __align__(16) float    ytile[NPIX * NCH];   // 25088 B
    __shared__ __align__(16) _Float16 t_lds[64 * TSTH];    //  5120 B

    const int tid = threadIdx.x;
    const int bx = blockIdx.x, by = blockIdx.y, bz = blockIdx.z;
    const int b = bz >> 1, half = bz & 1;
    const int gh0 = by * TILE, gw0 = bx * TILE;
    const int c0 = half * NCH;

    // ---- stage y halo tile: 32 ch x 14 x 14, swizzled channel-inner layout ----
    for (int li = tid; li < NCH * NPIX; li += 256) {
        int c    = li / NPIX;
        int pixl = li - c * NPIX;
        int rr   = pixl / HALO;
        int col  = pixl - rr * HALO;
        int grow = gh0 - PAD3 + rr;
        int gcol = gw0 - PAD3 + col;
        float v = 0.f;
        if ((unsigned)grow < 128u && (unsigned)gcol < 128u)
            v = y[((size_t)(b * C64 + c0 + c) << 14) + (grow << 7) + gcol];
        int slot = ((c >> 2) + pixl) & 7;
        ytile[pixl * NCH + slot * 4 + (c & 3)] = v;
    }

    // ---- phase 1: conv1 (1x1) + BN(eval) + ReLU -> t_lds as f16 [pixel][k] ----
    const int p  = tid & 63;                   // pixel within 8x8 tile (== lane)
    const int ph = p >> 3, pw = p & 7;
    const int oq = __builtin_amdgcn_readfirstlane(tid >> 6);  // wave id, uniform
    const int pix = ((gh0 + ph) << 7) + (gw0 + pw);
    {
        float dot[8] = {0,0,0,0,0,0,0,0};
        const float* w1q = w1 + oq * 8 * C64;
        const float* xp  = x + ((size_t)(b * C64) << 14) + pix;
        #pragma unroll 8
        for (int c = 0; c < C64; ++c) {
            float xc = xp[(size_t)c << 14];
            #pragma unroll
            for (int j = 0; j < 8; ++j) dot[j] += w1q[j * C64 + c] * xc;
        }
        _Float16 tv16[8];
        #pragma unroll
        for (int j = 0; j < 8; ++j) {
            int o = oq * 8 + j;
            float sv = gma[o] * rsqrtf(var[o] + EPSV);
            float bb = (b1[o] - mu[o]) * sv + bta[o];
            tv16[j] = (_Float16)fmaxf(dot[j] * sv + bb, 0.f);
        }
        *(half8*)&t_lds[p * TSTH + oq * 8] = *(const half8*)tv16;
    }
    __syncthreads();

    // ---- phase 2: MFMA conv2 + depthwise aggregation ----
    const int q = p >> 4;          // lane quadrant
    const int r = p & 15;

    // B fragments: B[k][col=pixel], lane holds k = 8q..8q+7, col = 16nt + r
    half8 bfrag[4];
    #pragma unroll
    for (int nt = 0; nt < 4; ++nt)
        bfrag[nt] = *(const half8*)&t_lds[(nt * 16 + r) * TSTH + q * 8];

    int pb[4];                     // pixel-base offsets into halo tile
    #pragma unroll
    for (int nt = 0; nt < 4; ++nt)
        pb[nt] = (2 * nt + (r >> 3)) * HALO + (r & 7);

    #pragma unroll 1
    for (int lgi = 0; lgi < 2; ++lgi) {
        const int lg = oq * 2 + lgi;           // local group 0..7 (wave-uniform)
        const int g  = half * NSL + lg;        // global group 0..15
        const float* w2g = w2 + g * 49 * CRED;
        const float* b2g = b2 + g * 49;

        float acc[4][4];                       // [nt][channel]
        #pragma unroll
        for (int nt = 0; nt < 4; ++nt)
            #pragma unroll
            for (int c = 0; c < 4; ++c) acc[nt][c] = 0.f;

        #pragma unroll
        for (int mt = 0; mt < 4; ++mt) {
            // A fragment: A[row=tap][k], lane holds row = 16mt + r, k = 8q..8q+7
            half8 af;
            {
                int row = mt * 16 + r;
                if (row < 49) {
                    const float* wr = w2g + row * CRED + q * 8;
                    float4 wa = *(const float4*)wr;
                    float4 wb = *(const float4*)(wr + 4);
                    af[0] = (_Float16)wa.x; af[1] = (_Float16)wa.y;
                    af[2] = (_Float16)wa.z; af[3] = (_Float16)wa.w;
                    af[4] = (_Float16)wb.x; af[5] = (_Float16)wb.y;
                    af[6] = (_Float16)wb.z; af[7] = (_Float16)wb.w;
                } else {
                    #pragma unroll
                    for (int j = 0; j < 8; ++j) af[j] = (_Float16)0.f;
                }
            }
            const f32x4 zero = {0.f, 0.f, 0.f, 0.f};
            f32x4 d[4];
            #pragma unroll
            for (int nt = 0; nt < 4; ++nt)
                d[nt] = __builtin_amdgcn_mfma_f32_16x16x32_f16(af, bfrag[nt], zero, 0, 0, 0);

            const int nreg = (mt < 3) ? 4 : 1;   // taps 49..63 are padding
            #pragma unroll
            for (int reg = 0; reg < 4; ++reg) {
                if (reg >= nreg) break;
                int tap0 = mt * 16 + q * 4 + reg;          // lane's tap (row)
                float bv;
                int tap;
                if (mt < 3) { bv = b2g[tap0]; tap = tap0; }
                else        { bv = (q == 0) ? b2g[48] : 0.f; tap = 48; }  // d==0 for pad rows
                int di = (tap * 9363) >> 16;               // tap / 7
                int tapoff = tap + 7 * di;                 // di*14 + dj
                #pragma unroll
                for (int nt = 0; nt < 4; ++nt) {
                    float wv = d[nt][reg] + bv;
                    int tp2 = pb[nt] + tapoff;
                    const float4 y4 = *(const float4*)&ytile[tp2 * NCH + (((lg + tp2) & 7) << 2)];
                    acc[nt][0] += wv * y4.x;
                    acc[nt][1] += wv * y4.y;
                    acc[nt][2] += wv * y4.z;
                    acc[nt][3] += wv * y4.w;
                }
            }
        }

        // reduce partial sums across quadrants (each quadrant covered a tap subset)
        #pragma unroll
        for (int nt = 0; nt < 4; ++nt)
            #pragma unroll
            for (int c = 0; c < 4; ++c) {
                float v = acc[nt][c];
                v += __shfl_xor(v, 16);
                v += __shfl_xor(v, 32);
                acc[nt][c] = v;
            }

        // lane p stores pixel p (= 16*q + r with nt = q)
        size_t ob = ((size_t)(b * C64 + g * GC4) << 14) + pix;
        #pragma unroll
        for (int c = 0; c < 4; ++c) {
            float s0 = (q & 1) ? acc[1][c] : acc[0][c];
            float s1 = (q & 1) ? acc[3][c] : acc[2][c];
            float vv = (q & 2) ? s1 : s0;
            out[ob + ((size_t)c << 14)] = vv;
        }
    }
}

extern "C" void kernel_launch(void* const* d_in, const int* in_sizes, int n_in,
                              void* d_out, int out_size, void* d_ws, size_t ws_size,
                              hipStream_t stream) {
    const float* x   = (const float*)d_in[0];
    const float* y   = (const float*)d_in[1];
    const float* w1  = (const float*)d_in[2];
    const float* b1  = (const float*)d_in[3];
    const float* gma = (const float*)d_in[4];
    const float* bta = (const float*)d_in[5];
    const float* mu  = (const float*)d_in[6];
    const float* var = (const float*)d_in[7];
    const float* w2  = (const float*)d_in[8];
    const float* b2  = (const float*)d_in[9];
    float* out = (float*)d_out;

    dim3 grid(128 / TILE, 128 / TILE, 8);   // 16 x 16 x (4 batch * 2 halves)
    dim3 block(256);
    hipLaunchKernelGGL(involution_mfma, grid, block, 0, stream,
                       x, y, w1, b1, gma, bta, mu, var, w2, b2, out);
}